// Round 7
// baseline (269.519 us; speedup 1.0000x reference)
//
#include <hip/hip_runtime.h>

#define B_SZ 1024
#define D_SZ 128
#define KTERMS 8
#define RSTRIDE 68   // uints/row: 64 data + 4 pad -> bank-balanced ds_read_b128
#define NBATCH 2     // batches per persistent block; grid = B_SZ/NBATCH = 512

typedef float vfloat4 __attribute__((ext_vector_type(4)));

__device__ inline float bflo(unsigned u) { return __uint_as_float(u << 16); }
__device__ inline float bfhi(unsigned u) { return __uint_as_float(u & 0xffff0000u); }

// 64-elem dot: bf16 row half from LDS (8 x ds_read_b128) x fp32 vector (broadcast)
__device__ inline float dotlds(const unsigned* rq, const float* v) {
    float a0 = 0.f, a1 = 0.f, a2 = 0.f, a3 = 0.f;
#pragma unroll
    for (int j = 0; j < 8; ++j) {
        uint4 qq = *(const uint4*)(rq + 4 * j);
        vfloat4 v0 = *(const vfloat4*)(v + 8 * j);
        vfloat4 v1 = *(const vfloat4*)(v + 8 * j + 4);
        a0 = fmaf(bflo(qq.x), v0.x, a0);
        a1 = fmaf(bfhi(qq.x), v0.y, a1);
        a2 = fmaf(bflo(qq.y), v0.z, a2);
        a3 = fmaf(bfhi(qq.y), v0.w, a3);
        a0 = fmaf(bflo(qq.z), v1.x, a0);
        a1 = fmaf(bfhi(qq.z), v1.y, a1);
        a2 = fmaf(bflo(qq.w), v1.z, a2);
        a3 = fmaf(bfhi(qq.w), v1.w, a3);
    }
    return (a0 + a1) + (a2 + a3);
}

// Persistent block: 2 batches.  Per batch:
//   P1: emit A1,A2 (nontemporal) + stage bf16(A0),bf16(W) into LDS
//   P3: 8-term Taylor expm (r3/r5-proven 2-round structure)
// Loads for batch g+1 are issued BEFORE P3(g) (into regs, asm-pinned) so the
// HBM read latency hides under the ~12us Taylor chain; A1/A2 stores of g+1
// drain under P3(g+1).  This breaks the P1/P3 phase lockstep that made r0-r5
// all land at ~92-95us (4 generations x (P1+P3) serialized).
__global__ void __launch_bounds__(512, 4)
magnus_kernel(const float* __restrict__ t0p, const float* __restrict__ hp,
              const float* __restrict__ y0, const float* __restrict__ A0,
              const float* __restrict__ W, float* __restrict__ out)
{
    __shared__ __align__(16) unsigned sA[D_SZ * RSTRIDE];  // 34,816 B
    __shared__ __align__(16) unsigned sW[D_SZ * RSTRIDE];  // 34,816 B
    __shared__ __align__(16) float sv[D_SZ];
    __shared__ __align__(16) float su1[D_SZ];
    __shared__ __align__(16) float su2[D_SZ];
    __shared__ __align__(16) float su3[D_SZ];
    __shared__ __align__(16) float su4[D_SZ];

    const int tid = threadIdx.x;
    const float h = hp[0];
    const float SQ3_6 = 0.28867513459481287f;  // sqrt(3)/6

    // phase-3 thread mapping (fixed across batches)
    const int grp  = tid >> 8;           // 0 = A0 rows, 1 = W rows
    const int t8   = tid & 255;
    const int half = (t8 >> 5) & 1;      // lane bit 5 -> shfl_xor(32) partner
    const int row  = (t8 & 31) + ((t8 >> 6) << 5);
    const unsigned* rq = (grp ? sW : sA) + row * RSTRIDE + half * 32;

    int b = blockIdx.x * NBATCH;

    // ---- prologue: load batch b into registers ----
    vfloat4 ra[8], rw[8];
    {
        const vfloat4* A0n = (const vfloat4*)(A0 + (size_t)b * (D_SZ * D_SZ));
        const vfloat4* Wn  = (const vfloat4*)(W  + (size_t)b * (D_SZ * D_SZ));
#pragma unroll
        for (int it = 0; it < 8; ++it) {
            int i = it * 512 + tid;
            ra[it] = A0n[i];
            rw[it] = Wn[i];
        }
    }

    for (int g = 0; g < NBATCH; ++g, ++b) {
        const float tb = t0p[b];
        const float t1 = tb + (0.5f - SQ3_6) * h;
        const float t2 = tb + (0.5f + SQ3_6) * h;
        const size_t moff = (size_t)b * (D_SZ * D_SZ);
        vfloat4* o1 = (vfloat4*)(out + (size_t)B_SZ * D_SZ + moff);
        vfloat4* o2 = (vfloat4*)(out + (size_t)B_SZ * D_SZ
                                     + (size_t)B_SZ * D_SZ * D_SZ + moff);

        // ---- P1: consume held regs -> A1/A2 stores + bf16 LDS staging ----
#pragma unroll
        for (int it = 0; it < 8; ++it) {
            int i = it * 512 + tid;
            vfloat4 a = ra[it], w = rw[it];
            vfloat4 p1, p2;
            p1.x = fmaf(t1, w.x, a.x); p1.y = fmaf(t1, w.y, a.y);
            p1.z = fmaf(t1, w.z, a.z); p1.w = fmaf(t1, w.w, a.w);
            p2.x = fmaf(t2, w.x, a.x); p2.y = fmaf(t2, w.y, a.y);
            p2.z = fmaf(t2, w.z, a.z); p2.w = fmaf(t2, w.w, a.w);
            __builtin_nontemporal_store(p1, o1 + i);
            __builtin_nontemporal_store(p2, o2 + i);

            unsigned pa0, pa1, pw0, pw1;
            asm("v_cvt_pk_bf16_f32 %0, %1, %2" : "=v"(pa0) : "v"(a.x), "v"(a.y));
            asm("v_cvt_pk_bf16_f32 %0, %1, %2" : "=v"(pa1) : "v"(a.z), "v"(a.w));
            asm("v_cvt_pk_bf16_f32 %0, %1, %2" : "=v"(pw0) : "v"(w.x), "v"(w.y));
            asm("v_cvt_pk_bf16_f32 %0, %1, %2" : "=v"(pw1) : "v"(w.z), "v"(w.w));
            int r = i >> 5;        // row 0..127
            int p = (2 * i) & 63;  // uint index within row (even)
            *(uint2*)(&sA[r * RSTRIDE + p]) = make_uint2(pa0, pa1);
            *(uint2*)(&sW[r * RSTRIDE + p]) = make_uint2(pw0, pw1);
        }

        float yacc = 0.0f;
        if (tid < D_SZ) {
            float v = y0[(size_t)b * D_SZ + tid];
            sv[tid] = v;
            yacc = v;
        }

        // ---- prefetch batch g+1 into regs; pin so loads issue NOW ----
        if (g + 1 < NBATCH) {
            const vfloat4* A0n = (const vfloat4*)(A0 + moff + D_SZ * D_SZ);
            const vfloat4* Wn  = (const vfloat4*)(W  + moff + D_SZ * D_SZ);
#pragma unroll
            for (int it = 0; it < 8; ++it) {
                int i = it * 512 + tid;
                ra[it] = A0n[i];
                rw[it] = Wn[i];
            }
#pragma unroll
            for (int it = 0; it < 8; ++it) {
                asm volatile("" : "+v"(ra[it]));
                asm volatile("" : "+v"(rw[it]));
            }
        }

        __syncthreads();  // staging + sv visible

        // ---- P3: 8-term Taylor, 2 matvec rounds per term ----
        const float hs = h * (tb + 0.5f * h);           // h * s
        const float c3 = h * h * h * (1.0f / 12.0f);    // h^3 / 12
#pragma unroll
        for (int k = 1; k <= KTERMS; ++k) {
            // Round A: u1 = A0 v (grp 0) | u2 = W v (grp 1)
            float a = dotlds(rq, sv + half * 64);
            a += __shfl_xor(a, 32);
            if (!half) { if (grp == 0) su1[row] = a; else su2[row] = a; }
            __syncthreads();
            // Round B: u3 = A0 u2 (grp 0) | u4 = W u1 (grp 1)
            const float* vb = grp ? su1 : su2;
            float c = dotlds(rq, vb + half * 64);
            c += __shfl_xor(c, 32);
            if (!half) { if (grp == 0) su3[row] = c; else su4[row] = c; }
            __syncthreads();
            if (tid < D_SZ) {
                float wn = h * su1[tid] + hs * su2[tid] - c3 * (su3[tid] - su4[tid]);
                wn *= (1.0f / (float)k);     // folds to constant (unrolled)
                yacc += wn;
                sv[tid] = wn;
            }
            __syncthreads();  // final instance also orders LDS reads vs restage
        }

        if (tid < D_SZ) {
            out[(size_t)b * D_SZ + tid] = yacc;
        }
        // no extra barrier needed: the k-loop's last __syncthreads() guarantees
        // no thread still reads sA/sW when the next iteration restages them.
    }
}

extern "C" void kernel_launch(void* const* d_in, const int* in_sizes, int n_in,
                              void* d_out, int out_size, void* d_ws, size_t ws_size,
                              hipStream_t stream) {
    const float* t0 = (const float*)d_in[0];
    const float* h  = (const float*)d_in[1];
    const float* y0 = (const float*)d_in[2];
    const float* A0 = (const float*)d_in[3];
    const float* W  = (const float*)d_in[4];
    float* out = (float*)d_out;
    magnus_kernel<<<B_SZ / NBATCH, 512, 0, stream>>>(t0, h, y0, A0, W, out);
}